// Round 1
// baseline (232.617 us; speedup 1.0000x reference)
//
#include <hip/hip_runtime.h>
#include <stdint.h>

constexpr int NB = 64;     // batch
constexpr int NT = 2048;   // time steps
constexpr int ND = 512;    // feature dim
constexpr int NU = 512;    // attention units

typedef float f32x4 __attribute__((ext_vector_type(4)));
typedef short bf16x8 __attribute__((ext_vector_type(8)));

__device__ __forceinline__ unsigned short f2bf(float x) {
  union { float f; unsigned int u; } v; v.f = x;
  unsigned int r = v.u + 0x7FFFu + ((v.u >> 16) & 1u);  // RNE
  return (unsigned short)(r >> 16);
}

__device__ __forceinline__ float fast_tanh(float x) {
  // exact at the tails (exp->0 or inf), ~1e-7 error midrange
  return 1.0f - 2.0f / (__expf(2.0f * x) + 1.0f);
}

// ---------------- K0a: q[b,u] = dh[b,:] @ W1[:,u] + b1[u] + b2[u] ----------------
__global__ __launch_bounds__(512) void qproj_kernel(
    const float* __restrict__ dh, const float* __restrict__ W1,
    const float* __restrict__ b1, const float* __restrict__ b2,
    float* __restrict__ q) {
  int b = blockIdx.x;
  int u = threadIdx.x;
  const float* dr = dh + b * ND;
  float a0 = 0.f, a1 = 0.f, a2 = 0.f, a3 = 0.f;
  for (int k = 0; k < ND; k += 4) {
    a0 = fmaf(dr[k + 0], W1[(size_t)(k + 0) * NU + u], a0);
    a1 = fmaf(dr[k + 1], W1[(size_t)(k + 1) * NU + u], a1);
    a2 = fmaf(dr[k + 2], W1[(size_t)(k + 2) * NU + u], a2);
    a3 = fmaf(dr[k + 3], W1[(size_t)(k + 3) * NU + u], a3);
  }
  q[b * NU + u] = b1[u] + b2[u] + ((a0 + a1) + (a2 + a3));
}

// ---------------- K0b: pack W2 (f32 [512,512]) -> bf16 B-fragment order ----------------
// layout: [ks 0..15][ntile 0..31][lane 0..63][8 bf16]
// frag element: col = ntile*16 + (lane&15), k = ks*32 + (lane>>4)*8 + j
__global__ __launch_bounds__(256) void packW2_kernel(
    const float* __restrict__ W2, unsigned short* __restrict__ w2p) {
  int tid = blockIdx.x * 256 + threadIdx.x;  // 0..32767
  int ks = tid >> 11;
  int rem = tid & 2047;
  int ntg = rem >> 6;
  int lane = rem & 63;
  int col = ntg * 16 + (lane & 15);
  int k0 = ks * 32 + ((lane >> 4) << 3);
  const float* src = W2 + (size_t)k0 * NU + col;
  ushort4 lo, hi;
  lo.x = f2bf(src[0 * NU]); lo.y = f2bf(src[1 * NU]);
  lo.z = f2bf(src[2 * NU]); lo.w = f2bf(src[3 * NU]);
  hi.x = f2bf(src[4 * NU]); hi.y = f2bf(src[5 * NU]);
  hi.z = f2bf(src[6 * NU]); hi.w = f2bf(src[7 * NU]);
  ushort4* dst = (ushort4*)(w2p + (size_t)tid * 8);
  dst[0] = lo; dst[1] = hi;
}

// ---------------- K2: fused logits = tanh(q + enc@W2) @ V   (bV dropped: softmax-invariant)
// grid 2048 = (b, tchunk of 64 rows); block 512 (8 waves), wave w owns N-chunk [w*64, w*64+64)
__global__ __launch_bounds__(512) void logits_kernel(
    const float* __restrict__ enc, const unsigned short* __restrict__ w2p,
    const float* __restrict__ q, const float* __restrict__ Vw,
    float* __restrict__ logits) {
  __shared__ unsigned short encA[64 * 512];   // 64KB bf16, XOR-swizzled rows
  __shared__ unsigned short w2s[16384];       // 32KB: one K-step of packed W2
  __shared__ float red[8][64];

  const int tid = threadIdx.x;
  const int wave = tid >> 6;
  const int lane = tid & 63;
  const int wg = blockIdx.x;
  const int b = wg >> 5;
  const int tch = wg & 31;

  const float4* encBase = (const float4*)(enc + ((size_t)b * NT + (size_t)tch * 64) * ND);

  // stage enc tile [64 rows x 512] f32 -> bf16 LDS, swizzle byte ^= ((row&7)<<4)
#pragma unroll
  for (int i = 0; i < 16; ++i) {
    int idx4 = i * 512 + tid;
    int row = idx4 >> 7;     // 128 float4 per row
    int c4 = idx4 & 127;
    float4 v = encBase[idx4];
    ushort4 h;
    h.x = f2bf(v.x); h.y = f2bf(v.y); h.z = f2bf(v.z); h.w = f2bf(v.w);
    int byteoff = row * 1024 + ((c4 * 8) ^ ((row & 7) << 4));
    *(ushort4*)((char*)encA + byteoff) = h;
  }

  // per-lane q and V for this wave's 64 output units
  float qv[4], Vv[4];
#pragma unroll
  for (int nt = 0; nt < 4; ++nt) {
    int col = wave * 64 + nt * 16 + (lane & 15);
    qv[nt] = q[b * NU + col];
    Vv[nt] = Vw[col];
  }

  f32x4 acc[4][4];
#pragma unroll
  for (int mt = 0; mt < 4; ++mt)
#pragma unroll
    for (int nt = 0; nt < 4; ++nt)
      acc[mt][nt] = (f32x4){0.0f, 0.0f, 0.0f, 0.0f};

  const int kgrp = (lane >> 4) << 4;  // byte offset of this lane's k-subgroup (8 bf16)
  int arowbase[4], aswz[4];
#pragma unroll
  for (int mt = 0; mt < 4; ++mt) {
    int row = mt * 16 + (lane & 15);
    arowbase[mt] = row * 1024;
    aswz[mt] = (row & 7) << 4;
  }

  for (int ks = 0; ks < 16; ++ks) {
    __syncthreads();  // prev-step B reads done (and encA staged, first iter)
    // stage this K-step's W2 fragments: 32KB linear via global_load_lds width-16
#pragma unroll
    for (int i = 0; i < 4; ++i) {
      const void* gsrc = (const char*)w2p + (size_t)ks * 32768 + i * 8192 + wave * 1024 + lane * 16;
      void* ldst = (char*)w2s + i * 8192 + wave * 1024;
      __builtin_amdgcn_global_load_lds((const __attribute__((address_space(1))) void*)gsrc,
                                       (__attribute__((address_space(3))) void*)ldst,
                                       16, 0, 0);
    }
    // A fragments from encA (stable all loop) — overlaps with the loads in flight
    bf16x8 afr[4];
#pragma unroll
    for (int mt = 0; mt < 4; ++mt) {
      int coff = (ks * 64 + kgrp) ^ aswz[mt];
      afr[mt] = *(const bf16x8*)((const char*)encA + arowbase[mt] + coff);
    }
    asm volatile("s_waitcnt vmcnt(0)" ::: "memory");
    __syncthreads();
    bf16x8 bfr[4];
#pragma unroll
    for (int nt = 0; nt < 4; ++nt) {
      int ntg = wave * 4 + nt;
      bfr[nt] = *(const bf16x8*)((const char*)w2s + (ntg * 64 + lane) * 16);
    }
#pragma unroll
    for (int mt = 0; mt < 4; ++mt)
#pragma unroll
      for (int nt = 0; nt < 4; ++nt)
        acc[mt][nt] = __builtin_amdgcn_mfma_f32_16x16x32_bf16(afr[mt], bfr[nt], acc[mt][nt], 0, 0, 0);
  }

  // epilogue: logit[row] = sum_u tanh(acc + q) * V[u]
  // D layout (m89): col = lane&15, row = (lane>>4)*4 + reg
#pragma unroll
  for (int mt = 0; mt < 4; ++mt) {
    float s0 = 0.f, s1 = 0.f, s2 = 0.f, s3 = 0.f;
#pragma unroll
    for (int nt = 0; nt < 4; ++nt) {
      s0 += fast_tanh(acc[mt][nt][0] + qv[nt]) * Vv[nt];
      s1 += fast_tanh(acc[mt][nt][1] + qv[nt]) * Vv[nt];
      s2 += fast_tanh(acc[mt][nt][2] + qv[nt]) * Vv[nt];
      s3 += fast_tanh(acc[mt][nt][3] + qv[nt]) * Vv[nt];
    }
    float sr[4] = {s0, s1, s2, s3};
#pragma unroll
    for (int r = 0; r < 4; ++r) {
      float v = sr[r];
      v += __shfl_xor(v, 1);
      v += __shfl_xor(v, 2);
      v += __shfl_xor(v, 4);
      v += __shfl_xor(v, 8);
      if ((lane & 15) == 0) red[wave][mt * 16 + ((lane >> 4) << 2) + r] = v;
    }
  }
  __syncthreads();
  if (tid < 64) {
    float t = 0.f;
#pragma unroll
    for (int w = 0; w < 8; ++w) t += red[w][tid];
    logits[(size_t)b * NT + (size_t)tch * 64 + tid] = t;
  }
}

// ---------------- K3: in-place softmax over T per batch ----------------
__global__ __launch_bounds__(512) void softmax_kernel(float* __restrict__ wts) {
  int b = blockIdx.x;
  int tid = threadIdx.x;
  float4* base = (float4*)(wts + (size_t)b * NT);
  float4 v = base[tid];
  float m = fmaxf(fmaxf(v.x, v.y), fmaxf(v.z, v.w));
#pragma unroll
  for (int d = 1; d < 64; d <<= 1) m = fmaxf(m, __shfl_xor(m, d));
  __shared__ float sm[8];
  __shared__ float ss[8];
  int w = tid >> 6;
  if ((tid & 63) == 0) sm[w] = m;
  __syncthreads();
  float M = sm[0];
#pragma unroll
  for (int i = 1; i < 8; ++i) M = fmaxf(M, sm[i]);
  float e0 = __expf(v.x - M), e1 = __expf(v.y - M), e2 = __expf(v.z - M), e3 = __expf(v.w - M);
  float s = e0 + e1 + e2 + e3;
#pragma unroll
  for (int d = 1; d < 64; d <<= 1) s += __shfl_xor(s, d);
  if ((tid & 63) == 0) ss[w] = s;
  __syncthreads();
  float S = 0.f;
#pragma unroll
  for (int i = 0; i < 8; ++i) S += ss[i];
  float inv = 1.0f / S;
  base[tid] = (float4){e0 * inv, e1 * inv, e2 * inv, e3 * inv};
}

// ---------------- K4: context partials over t-slices (f32, coalesced) ----------------
__global__ __launch_bounds__(512) void ctx_partial_kernel(
    const float* __restrict__ enc, const float* __restrict__ wts,
    float* __restrict__ partials) {
  int bx = blockIdx.x;          // b*16 + slice
  int b = bx >> 4;
  int slice = bx & 15;
  int tid = threadIdx.x;        // d index
  const float* e = enc + ((size_t)b * NT + (size_t)slice * 128) * ND + tid;
  const float* wp = wts + (size_t)b * NT + slice * 128;
  float acc = 0.0f;
#pragma unroll 4
  for (int tt = 0; tt < 128; ++tt) {
    acc = fmaf(wp[tt], e[(size_t)tt * ND], acc);
  }
  partials[(size_t)bx * ND + tid] = acc;
}

__global__ __launch_bounds__(512) void ctx_combine_kernel(
    const float* __restrict__ partials, float* __restrict__ ctx) {
  int b = blockIdx.x;
  int tid = threadIdx.x;
  float s = 0.0f;
#pragma unroll
  for (int i = 0; i < 16; ++i) s += partials[((size_t)b * 16 + i) * ND + tid];
  ctx[(size_t)b * ND + tid] = s;
}

// ---------------- launch ----------------
extern "C" void kernel_launch(void* const* d_in, const int* in_sizes, int n_in,
                              void* d_out, int out_size, void* d_ws, size_t ws_size,
                              hipStream_t stream) {
  const float* dh  = (const float*)d_in[0];
  const float* enc = (const float*)d_in[1];
  const float* W1  = (const float*)d_in[2];
  const float* b1  = (const float*)d_in[3];
  const float* W2  = (const float*)d_in[4];
  const float* b2  = (const float*)d_in[5];
  const float* Vw  = (const float*)d_in[6];
  // d_in[7] = bV: softmax is shift-invariant and logits are not an output -> unused

  // workspace layout
  float* q            = (float*)d_ws;                                  // 128KB
  unsigned short* w2p = (unsigned short*)((char*)d_ws + 131072);       // 512KB packed bf16
  float* partials     = (float*)((char*)d_ws + 655360);                // 2MB

  float* ctx = (float*)d_out;                 // [64,512]
  float* wts = (float*)d_out + NB * ND;       // [64,2048] (logits, then softmaxed in place)

  qproj_kernel<<<NB, 512, 0, stream>>>(dh, W1, b1, b2, q);
  packW2_kernel<<<128, 256, 0, stream>>>(W2, w2p);
  logits_kernel<<<NB * (NT / 64), 512, 0, stream>>>(enc, w2p, q, Vw, wts);
  softmax_kernel<<<NB, 512, 0, stream>>>(wts);
  ctx_partial_kernel<<<NB * 16, 512, 0, stream>>>(enc, wts, partials);
  ctx_combine_kernel<<<NB, 512, 0, stream>>>(partials, ctx);
}

// Round 2
// 171.249 us; speedup vs baseline: 1.3584x; 1.3584x over previous
//
#include <hip/hip_runtime.h>
#include <stdint.h>

constexpr int NB = 64;     // batch
constexpr int NT = 2048;   // time steps
constexpr int ND = 512;    // feature dim
constexpr int NU = 512;    // attention units

typedef float f32x4 __attribute__((ext_vector_type(4)));
typedef short bf16x8 __attribute__((ext_vector_type(8)));

__device__ __forceinline__ unsigned short f2bf(float x) {
  union { float f; unsigned int u; } v; v.f = x;
  unsigned int r = v.u + 0x7FFFu + ((v.u >> 16) & 1u);  // RNE
  return (unsigned short)(r >> 16);
}

__device__ __forceinline__ float fast_tanh(float x) {
  // exact at the tails (exp->0 or inf), ~1e-7 error midrange
  return 1.0f - 2.0f / (__expf(2.0f * x) + 1.0f);
}

// ---------------- K0a: q[b,u] = dh[b,:] @ W1[:,u] + b1[u] + b2[u] ----------------
__global__ __launch_bounds__(512) void qproj_kernel(
    const float* __restrict__ dh, const float* __restrict__ W1,
    const float* __restrict__ b1, const float* __restrict__ b2,
    float* __restrict__ q) {
  int b = blockIdx.x;
  int u = threadIdx.x;
  const float* dr = dh + b * ND;
  float a0 = 0.f, a1 = 0.f, a2 = 0.f, a3 = 0.f;
  for (int k = 0; k < ND; k += 4) {
    a0 = fmaf(dr[k + 0], W1[(size_t)(k + 0) * NU + u], a0);
    a1 = fmaf(dr[k + 1], W1[(size_t)(k + 1) * NU + u], a1);
    a2 = fmaf(dr[k + 2], W1[(size_t)(k + 2) * NU + u], a2);
    a3 = fmaf(dr[k + 3], W1[(size_t)(k + 3) * NU + u], a3);
  }
  q[b * NU + u] = b1[u] + b2[u] + ((a0 + a1) + (a2 + a3));
}

// ---------------- K0b: pack W2 (f32 [512,512]) -> bf16 B-fragment order ----------------
// layout: [ks 0..15][ntg 0..31][lane 0..63][8 bf16]
// frag element: col = ntg*16 + (lane&15), k = ks*32 + (lane>>4)*8 + j
__global__ __launch_bounds__(256) void packW2_kernel(
    const float* __restrict__ W2, unsigned short* __restrict__ w2p) {
  int tid = blockIdx.x * 256 + threadIdx.x;  // 0..32767
  int ks = tid >> 11;
  int rem = tid & 2047;
  int ntg = rem >> 6;
  int lane = rem & 63;
  int col = ntg * 16 + (lane & 15);
  int k0 = ks * 32 + ((lane >> 4) << 3);
  const float* src = W2 + (size_t)k0 * NU + col;
  ushort4 lo, hi;
  lo.x = f2bf(src[0 * NU]); lo.y = f2bf(src[1 * NU]);
  lo.z = f2bf(src[2 * NU]); lo.w = f2bf(src[3 * NU]);
  hi.x = f2bf(src[4 * NU]); hi.y = f2bf(src[5 * NU]);
  hi.z = f2bf(src[6 * NU]); hi.w = f2bf(src[7 * NU]);
  ushort4* dst = (ushort4*)(w2p + (size_t)tid * 8);
  dst[0] = lo; dst[1] = hi;
}

// ---------------- K2: fused logits = tanh(q + enc@W2) @ V   (bV dropped: softmax-invariant)
// grid 2048 = (b, tchunk of 64 rows); block 512 (8 waves), wave w owns units [w*64, w*64+64)
// A tile (64 rows x full K=512) staged ONCE in LDS (bf16, XOR-swizzled) -> one barrier.
// B fragments come straight from L2 (w2p is 512KB, L2-resident) with 1-deep reg prefetch.
// K-loop is barrier-free; 2 blocks/CU (66KB LDS) give inter-block latency hiding.
__global__ __launch_bounds__(512, 4) void logits_kernel(
    const float* __restrict__ enc, const unsigned short* __restrict__ w2p,
    const float* __restrict__ q, const float* __restrict__ Vw,
    float* __restrict__ logits) {
  __shared__ unsigned short encA[64 * 512];   // 64KB bf16, XOR-swizzled rows
  __shared__ float red[8][64];

  const int tid = threadIdx.x;
  const int wave = tid >> 6;
  const int lane = tid & 63;
  const int wg = blockIdx.x;
  const int b = wg >> 5;
  const int tch = wg & 31;

  const float4* encBase = (const float4*)(enc + ((size_t)b * NT + (size_t)tch * 64) * ND);

  // stage enc tile [64 rows x 512] f32 -> bf16 LDS, swizzle byte ^= ((row&7)<<4)
#pragma unroll
  for (int i = 0; i < 16; ++i) {
    int idx4 = i * 512 + tid;
    int row = idx4 >> 7;     // 128 float4 per row
    int c4 = idx4 & 127;
    float4 v = encBase[idx4];
    ushort4 h;
    h.x = f2bf(v.x); h.y = f2bf(v.y); h.z = f2bf(v.z); h.w = f2bf(v.w);
    int byteoff = row * 1024 + ((c4 * 8) ^ ((row & 7) << 4));
    *(ushort4*)((char*)encA + byteoff) = h;
  }

  // per-lane q and V for this wave's 64 output units
  float qv[4], Vv[4];
#pragma unroll
  for (int nt = 0; nt < 4; ++nt) {
    int col = wave * 64 + nt * 16 + (lane & 15);
    qv[nt] = q[b * NU + col];
    Vv[nt] = Vw[col];
  }

  f32x4 acc[4][4];
#pragma unroll
  for (int mt = 0; mt < 4; ++mt)
#pragma unroll
    for (int nt = 0; nt < 4; ++nt)
      acc[mt][nt] = (f32x4){0.0f, 0.0f, 0.0f, 0.0f};

  const int kgrp = (lane >> 4) << 4;  // byte offset of this lane's k-subgroup (8 bf16)
  int arowbase[4], aswz[4];
#pragma unroll
  for (int mt = 0; mt < 4; ++mt) {
    int row = mt * 16 + (lane & 15);
    arowbase[mt] = row * 1024;
    aswz[mt] = (row & 7) << 4;
  }

  // B fragment byte offset: ks*32768 + (wave*4+nt)*1024 + lane*16
  const char* bbase = (const char*)w2p + (size_t)(wave * 4) * 1024 + (size_t)lane * 16;

  // prologue: B frags for ks=0 (no LDS dependency -> overlaps staging)
  bf16x8 bcu[4];
#pragma unroll
  for (int nt = 0; nt < 4; ++nt)
    bcu[nt] = *(const bf16x8*)(bbase + nt * 1024);

  __syncthreads();  // A staged; the ONLY barrier before the epilogue

#pragma unroll
  for (int ks = 0; ks < 16; ++ks) {
    bf16x8 bnx[4];
    if (ks < 15) {
#pragma unroll
      for (int nt = 0; nt < 4; ++nt)
        bnx[nt] = *(const bf16x8*)(bbase + (ks + 1) * 32768 + nt * 1024);
    }
    bf16x8 afr[4];
#pragma unroll
    for (int mt = 0; mt < 4; ++mt) {
      int coff = (ks * 64 + kgrp) ^ aswz[mt];
      afr[mt] = *(const bf16x8*)((const char*)encA + arowbase[mt] + coff);
    }
    __builtin_amdgcn_s_setprio(1);
#pragma unroll
    for (int mt = 0; mt < 4; ++mt)
#pragma unroll
      for (int nt = 0; nt < 4; ++nt)
        acc[mt][nt] = __builtin_amdgcn_mfma_f32_16x16x32_bf16(afr[mt], bcu[nt], acc[mt][nt], 0, 0, 0);
    __builtin_amdgcn_s_setprio(0);
    if (ks < 15) {
#pragma unroll
      for (int nt = 0; nt < 4; ++nt) bcu[nt] = bnx[nt];
    }
  }

  // epilogue: logit[row] = sum_u tanh(acc + q) * V[u]
  // D layout (m89): col = lane&15, row = (lane>>4)*4 + reg
#pragma unroll
  for (int mt = 0; mt < 4; ++mt) {
    float s0 = 0.f, s1 = 0.f, s2 = 0.f, s3 = 0.f;
#pragma unroll
    for (int nt = 0; nt < 4; ++nt) {
      s0 += fast_tanh(acc[mt][nt][0] + qv[nt]) * Vv[nt];
      s1 += fast_tanh(acc[mt][nt][1] + qv[nt]) * Vv[nt];
      s2 += fast_tanh(acc[mt][nt][2] + qv[nt]) * Vv[nt];
      s3 += fast_tanh(acc[mt][nt][3] + qv[nt]) * Vv[nt];
    }
    float sr[4] = {s0, s1, s2, s3};
#pragma unroll
    for (int r = 0; r < 4; ++r) {
      float v = sr[r];
      v += __shfl_xor(v, 1);
      v += __shfl_xor(v, 2);
      v += __shfl_xor(v, 4);
      v += __shfl_xor(v, 8);
      if ((lane & 15) == 0) red[wave][mt * 16 + ((lane >> 4) << 2) + r] = v;
    }
  }
  __syncthreads();
  if (tid < 64) {
    float t = 0.f;
#pragma unroll
    for (int w = 0; w < 8; ++w) t += red[w][tid];
    logits[(size_t)b * NT + (size_t)tch * 64 + tid] = t;
  }
}

// ---------------- K3: in-place softmax over T per batch ----------------
__global__ __launch_bounds__(512) void softmax_kernel(float* __restrict__ wts) {
  int b = blockIdx.x;
  int tid = threadIdx.x;
  float4* base = (float4*)(wts + (size_t)b * NT);
  float4 v = base[tid];
  float m = fmaxf(fmaxf(v.x, v.y), fmaxf(v.z, v.w));
#pragma unroll
  for (int d = 1; d < 64; d <<= 1) m = fmaxf(m, __shfl_xor(m, d));
  __shared__ float sm[8];
  __shared__ float ss[8];
  int w = tid >> 6;
  if ((tid & 63) == 0) sm[w] = m;
  __syncthreads();
  float M = sm[0];
#pragma unroll
  for (int i = 1; i < 8; ++i) M = fmaxf(M, sm[i]);
  float e0 = __expf(v.x - M), e1 = __expf(v.y - M), e2 = __expf(v.z - M), e3 = __expf(v.w - M);
  float s = e0 + e1 + e2 + e3;
#pragma unroll
  for (int d = 1; d < 64; d <<= 1) s += __shfl_xor(s, d);
  if ((tid & 63) == 0) ss[w] = s;
  __syncthreads();
  float S = 0.f;
#pragma unroll
  for (int i = 0; i < 8; ++i) S += ss[i];
  float inv = 1.0f / S;
  base[tid] = (float4){e0 * inv, e1 * inv, e2 * inv, e3 * inv};
}

// ---------------- K4: context partials over t-slices (f32, coalesced) ----------------
__global__ __launch_bounds__(512) void ctx_partial_kernel(
    const float* __restrict__ enc, const float* __restrict__ wts,
    float* __restrict__ partials) {
  int bx = blockIdx.x;          // b*16 + slice
  int b = bx >> 4;
  int slice = bx & 15;
  int tid = threadIdx.x;        // d index
  const float* e = enc + ((size_t)b * NT + (size_t)slice * 128) * ND + tid;
  const float* wp = wts + (size_t)b * NT + slice * 128;
  float acc = 0.0f;
#pragma unroll 4
  for (int tt = 0; tt < 128; ++tt) {
    acc = fmaf(wp[tt], e[(size_t)tt * ND], acc);
  }
  partials[(size_t)bx * ND + tid] = acc;
}

__global__ __launch_bounds__(512) void ctx_combine_kernel(
    const float* __restrict__ partials, float* __restrict__ ctx) {
  int b = blockIdx.x;
  int tid = threadIdx.x;
  float s = 0.0f;
#pragma unroll
  for (int i = 0; i < 16; ++i) s += partials[((size_t)b * 16 + i) * ND + tid];
  ctx[(size_t)b * ND + tid] = s;
}

// ---------------- launch ----------------
extern "C" void kernel_launch(void* const* d_in, const int* in_sizes, int n_in,
                              void* d_out, int out_size, void* d_ws, size_t ws_size,
                              hipStream_t stream) {
  const float* dh  = (const float*)d_in[0];
  const float* enc = (const float*)d_in[1];
  const float* W1  = (const float*)d_in[2];
  const float* b1  = (const float*)d_in[3];
  const float* W2  = (const float*)d_in[4];
  const float* b2  = (const float*)d_in[5];
  const float* Vw  = (const float*)d_in[6];
  // d_in[7] = bV: softmax is shift-invariant and logits are not an output -> unused

  // workspace layout
  float* q            = (float*)d_ws;                                  // 128KB
  unsigned short* w2p = (unsigned short*)((char*)d_ws + 131072);       // 512KB packed bf16
  float* partials     = (float*)((char*)d_ws + 655360);                // 2MB

  float* ctx = (float*)d_out;                 // [64,512]
  float* wts = (float*)d_out + NB * ND;       // [64,2048] (logits, then softmaxed in place)

  qproj_kernel<<<NB, 512, 0, stream>>>(dh, W1, b1, b2, q);
  packW2_kernel<<<128, 256, 0, stream>>>(W2, w2p);
  logits_kernel<<<NB * (NT / 64), 512, 0, stream>>>(enc, w2p, q, Vw, wts);
  softmax_kernel<<<NB, 512, 0, stream>>>(wts);
  ctx_partial_kernel<<<NB * 16, 512, 0, stream>>>(enc, wts, partials);
  ctx_combine_kernel<<<NB, 512, 0, stream>>>(partials, ctx);
}